// Round 3
// baseline (513.040 us; speedup 1.0000x reference)
//
#include <hip/hip_runtime.h>
#include <math.h>

#define N_ANGLES 180
#define P 724
#define W_IN 512

typedef float vfloat4 __attribute__((ext_vector_type(4)));

// ---------------- prep kernel: transpose + trig table ----------------
// ws[0..359] = {cos,sin} per angle (float2); ws+512 .. = transposed image
__global__ __launch_bounds__(256) void prep_all(const float* __restrict__ in,
                                                float* __restrict__ outT,
                                                float2* __restrict__ sc) {
    __shared__ float tile[32][33];
    const int bx = blockIdx.x * 32, by = blockIdx.y * 32;
    const int tx = threadIdx.x, ty = threadIdx.y;   // block (32,8)

    if (bx == 0 && by == 0) {
        int t = ty * 32 + tx;
        if (t < N_ANGLES) {
            float deg = (float)t * (180.0f / 179.0f);
            float ang = deg * (float)(M_PI / 180.0);
            sc[t] = make_float2(cosf(ang), sinf(ang));
        }
    }

    #pragma unroll
    for (int r = 0; r < 32; r += 8)
        tile[ty + r][tx] = in[(by + ty + r) * W_IN + bx + tx];
    __syncthreads();
    #pragma unroll
    for (int r = 0; r < 32; r += 8)
        outT[(bx + ty + r) * W_IN + by + tx] = tile[tx][ty + r];
}

// ---------------- main kernel ----------------
// One block = one output row (a,i). 192 threads; threads 0..180 each produce a
// quad of 4 consecutive pixels and one 16B nontemporal store (181*4 == 724).
// MODE 2: trig+transpose from ws | MODE 1: trig only | MODE 0: standalone
template <int MODE>
__global__ __launch_bounds__(192) void radon_kernel(
    const float* __restrict__ x,       // [512,512]
    const float2* __restrict__ sc,     // [180] {c,s}
    const float* __restrict__ xT,      // [512,512] transposed (MODE==2)
    float* __restrict__ sino,          // [180,724]
    float* __restrict__ rot)           // [180,724,724]
{
    const int block = blockIdx.x;          // 0 .. 180*724-1
    const int a = block / P;
    const int i = block - a * P;
    const int tid = threadIdx.x;

    float c, s;
    if (MODE > 0) {
        float2 cs = sc[a];
        c = cs.x; s = cs.y;
    } else {
        float deg = (float)a * (180.0f / 179.0f);
        float ang = deg * (float)(M_PI / 180.0);
        c = cosf(ang); s = sinf(ang);
    }

    // ix = c*j + Kx, iy = s*j + Ky  (unpadded input coords; PAD folded in)
    const float fi = (float)i - 361.5f;
    const float Kx = 255.5f - 361.5f * c - s * fi;
    const float Ky = 255.5f - 361.5f * s + c * fi;

    // block-uniform axis swap: fast-axis = contiguous in the image we gather from
    const bool useT = (MODE == 2) && (fabsf(s) > fabsf(c));
    const float* __restrict__ bimg = useT ? xT : x;
    const float fcoef = useT ? s : c;      // fast (contiguous) axis
    const float fK    = useT ? Ky : Kx;
    const float scoef = useT ? c : s;      // slow (row-stride 512) axis
    const float sK    = useT ? Kx : Ky;

    // ---- analytic nonzero span: sample != 0 requires ix,iy in (-1,512) ----
    float lo = 0.0f, hi = 723.0f;
    bool empty = false;
    {
        if (fabsf(c) >= 1e-3f) {
            float rc = 1.0f / c;
            float b1 = (-1.0f - Kx) * rc, b2 = (512.0f - Kx) * rc;
            lo = fmaxf(lo, fminf(b1, b2)); hi = fminf(hi, fmaxf(b1, b2));
        } else if (Kx <= -1.0f || Kx >= 512.0f) empty = true;
        if (fabsf(s) >= 1e-3f) {
            float rs = 1.0f / s;
            float b1 = (-1.0f - Ky) * rs, b2 = (512.0f - Ky) * rs;
            lo = fmaxf(lo, fminf(b1, b2)); hi = fminf(hi, fmaxf(b1, b2));
        } else if (Ky <= -1.0f || Ky >= 512.0f) empty = true;
    }
    int jlo, jhi;
    if (empty || lo > hi) { jlo = 1; jhi = 0; }
    else {
        jlo = max(0, (int)floorf(lo) - 2);    // widen 2 px: covers fp boundary error
        jhi = min(723, (int)ceilf(hi) + 2);
    }

    float* rrow = rot + (size_t)block * P;
    float lsum = 0.0f;

    if (tid < 181) {
        const int j0 = tid << 2;
        vfloat4 o;
        if (j0 + 3 < jlo || j0 > jhi) {
            o = (vfloat4){0.0f, 0.0f, 0.0f, 0.0f};
        } else {
            // coords for the 4 samples (linear in j)
            const float jf = (float)j0;
            float fcv[4], scv[4];
            fcv[0] = fmaf(jf, fcoef, fK);
            scv[0] = fmaf(jf, scoef, sK);
            #pragma unroll
            for (int d = 1; d < 4; ++d) { fcv[d] = fcv[d-1] + fcoef; scv[d] = scv[d-1] + scoef; }

            float f0f[4], s0f[4];
            int f0i[4], s0i[4];
            bool interior = true;
            #pragma unroll
            for (int d = 0; d < 4; ++d) {
                f0f[d] = floorf(fcv[d]); s0f[d] = floorf(scv[d]);
                f0i[d] = (int)f0f[d];    s0i[d] = (int)s0f[d];
                interior = interior && ((unsigned)f0i[d] < 511u) && ((unsigned)s0i[d] < 511u);
            }

            float v[4];
            if (__all((int)interior)) {
                // fully interior wave: 1 base per sample, imm-offset taps
                #pragma unroll
                for (int d = 0; d < 4; ++d) {
                    const float wf1 = fcv[d] - f0f[d], wf0 = 1.0f - wf1;
                    const float ws1 = scv[d] - s0f[d], ws0 = 1.0f - ws1;
                    const float* bp = bimg + (s0i[d] << 9) + f0i[d];
                    const float v00 = bp[0],   vA = bp[1];
                    const float vB  = bp[512], v11 = bp[513];
                    v[d] = fmaf(ws1, fmaf(wf1, v11, wf0 * vB),
                                ws0 * fmaf(wf1, vA, wf0 * v00));
                }
            } else {
                // boundary: fold oob masks into weights, clamp indices
                #pragma unroll
                for (int d = 0; d < 4; ++d) {
                    const int fa = f0i[d], fb = fa + 1;
                    const int sa = s0i[d], sb = sa + 1;
                    float wf1 = fcv[d] - f0f[d], wf0 = 1.0f - wf1;
                    float ws1 = scv[d] - s0f[d], ws0 = 1.0f - ws1;
                    wf0 = ((unsigned)fa < 512u) ? wf0 : 0.0f;
                    wf1 = ((unsigned)fb < 512u) ? wf1 : 0.0f;
                    ws0 = ((unsigned)sa < 512u) ? ws0 : 0.0f;
                    ws1 = ((unsigned)sb < 512u) ? ws1 : 0.0f;
                    const int fca = min(max(fa, 0), 511);
                    const int fcb = min(max(fb, 0), 511);
                    const int sca = min(max(sa, 0), 511);
                    const int scb = min(max(sb, 0), 511);
                    const float v00 = bimg[(sca << 9) + fca];
                    const float v01 = bimg[(sca << 9) + fcb];
                    const float v10 = bimg[(scb << 9) + fca];
                    const float v11 = bimg[(scb << 9) + fcb];
                    v[d] = fmaf(ws1, fmaf(wf1, v11, wf0 * v10),
                                ws0 * fmaf(wf1, v01, wf0 * v00));
                }
            }
            o = (vfloat4){v[0], v[1], v[2], v[3]};
        }
        __builtin_nontemporal_store(o, (vfloat4*)(rrow + j0));
        lsum = (o.x + o.y) + (o.z + o.w);
    }

    // block reduction: wave64 shuffle, then cross-wave via LDS (3 waves)
    for (int off = 32; off > 0; off >>= 1)
        lsum += __shfl_down(lsum, off, 64);

    __shared__ float ws_red[3];
    const int lane = tid & 63;
    const int wid  = tid >> 6;
    if (lane == 0) ws_red[wid] = lsum;
    __syncthreads();
    if (tid == 0)
        sino[block] = ws_red[0] + ws_red[1] + ws_red[2];
}

// ---------------- launch ----------------

extern "C" void kernel_launch(void* const* d_in, const int* in_sizes, int n_in,
                              void* d_out, int out_size, void* d_ws, size_t ws_size,
                              hipStream_t stream) {
    const float* x = (const float*)d_in[0];
    float* sino = (float*)d_out;                       // [180*724]
    float* rot  = sino + (size_t)N_ANGLES * P;         // [180*724*724]
    float* ws   = (float*)d_ws;

    const dim3 grid(N_ANGLES * P), blk(192);
    if (ws && ws_size >= (size_t)(512 + 512 * 512) * sizeof(float)) {
        float* xT = ws + 512;
        prep_all<<<dim3(16, 16), dim3(32, 8), 0, stream>>>(x, xT, (float2*)ws);
        radon_kernel<2><<<grid, blk, 0, stream>>>(x, (const float2*)ws, xT, sino, rot);
    } else if (ws && ws_size >= (size_t)512 * sizeof(float)) {
        prep_all<<<dim3(16, 16), dim3(32, 8), 0, stream>>>(x, nullptr, (float2*)ws); // trig only (outT unused)
        radon_kernel<1><<<grid, blk, 0, stream>>>(x, (const float2*)ws, nullptr, sino, rot);
    } else {
        radon_kernel<0><<<grid, blk, 0, stream>>>(x, nullptr, nullptr, sino, rot);
    }
}